// Round 8
// baseline (405.655 us; speedup 1.0000x reference)
//
#include <hip/hip_runtime.h>
#include <stdint.h>

// Spiking ConvColumn: temporal PWL-response conv + winner-takes-all.
//   input_spikes [16, 2, 64, 64, 100] fp32 (binary)
//   weight       [32, 2, 3, 3]        fp32 in [0,1]
//   output       [16, 32, 31, 31, 149] fp32 (one-hot spikes)
#define NXS 31
#define NYS 31
#define TP 149
#define TT 100
#define RSTRIDE 108         // u32/row: 101 entries + 7 spare; 108%32=12 ->
                            // b128 build stores <=2-way bank alias (free);
                            // 108%4==0 keeps 16-B alignment for b128.
#define NROWS 54            // 2 ci * 3 ky * 9 cols (4 sites share 9 cols)
#define LDS_TBL (NROWS * RSTRIDE)   // 5832 u32 = 23.3 KB
#define LDS_MSK (4 * 32 * 6)        // per-(site,ch) 5-word masks (pad to 6)
                                    // total 26.3 KB -> 6 blocks/CU

// Block = 4 waves = sites x0..x0+3 sharing one table set (9 columns).
// Wave lanes: 0-31 = 32 ch x trains 0-8 (ci=0); 32-63 = same ch x 9-17 (ci=1).
// Table entry k = (C[k]<<16)|M[k]: C = #spikes before time k, M = sum times.
// Indices clamp two-sided (R5-verified): clamp(i,0,100); T[0]=0, T[100]=total.
__global__ __launch_bounds__(256) void snn_wta(
    const float* __restrict__ in,
    const float* __restrict__ weight,
    float* __restrict__ out)
{
    __shared__ uint32_t lds[LDS_TBL + LDS_MSK];
    uint32_t* tbl  = lds;
    uint32_t* mlds = lds + LDS_TBL;

    const int tid  = threadIdx.x;
    const int wave = tid >> 6;
    const int lane = tid & 63;
    const int half = lane >> 5;
    const int ch   = lane & 31;

    const int bi = blockIdx.x;
    const int xg = bi & 7;                // 8 x-groups of 4 (last has 3)
    const int y  = (bi >> 3) % NYS;
    const int b  = bi / (8 * NYS);
    const int x0 = xg * 4;
    const int x  = x0 + wave;             // this wave's site (x>=31 inactive)

    // per-lane response params: r(tau)=tau/16 for tau<=m=floor(16w);
    // (48w-tau)/32 for m<tau<=n=ceil(48w)-1.
    float wA[9]; int mA[9], nA[9];
    {
        const float* wrow = weight + ch * 18 + half * 9;
#pragma unroll
        for (int j = 0; j < 9; ++j) {
            float w = wrow[j];
            float a48 = 48.0f * w;
            int m = (int)floorf(16.0f * w);
            int n = (int)ceilf(a48) - 1;
            if (n < m) n = m;
            wA[j] = a48; mA[j] = m; nA[j] = n;
        }
    }

    // ---- build 54 rows; row r owned by one lane (waves split the rows).
    // Tree-form prefix: 25-step carry chain, b128 entry stores.
    {
        const int r = lane + 14 * wave;    // lanes 0..13 of each wave
        if (lane < 14 && r < NROWS) {
            const int ci = r / 27, rem = r % 27;
            const int ky = rem / 9, col = rem % 9;
            const int h = 2 * y + ky, wc = 2 * x0 + col;
            if (wc < 64) {                 // xg=7,col=8 is OOB and unused
                const float4* rowp = (const float4*)(in +
                    (size_t)(((b * 2 + ci) * 64 + h) * 64 + wc) * TT);
                uint32_t* t = tbl + r * RSTRIDE;      // entry-0, 16B aligned
                uint32_t run = 0;
#pragma unroll 5
                for (int chunk = 0; chunk < 25; ++chunk) {
                    float4 v = rowp[chunk];
                    const uint32_t u = chunk * 4;
                    uint32_t i0 = (v.x > 0.5f) ? ((1u << 16) | u)       : 0u;
                    uint32_t i1 = (v.y > 0.5f) ? ((1u << 16) | (u + 1)) : 0u;
                    uint32_t i2 = (v.z > 0.5f) ? ((1u << 16) | (u + 2)) : 0u;
                    uint32_t i3 = (v.w > 0.5f) ? ((1u << 16) | (u + 3)) : 0u;
                    uint32_t s01 = i0 + i1;
                    uint32_t e1 = run + i0;
                    uint32_t e2 = run + s01;
                    uint32_t e3 = e2 + i2;
                    *((uint4*)(t + u)) = make_uint4(run, e1, e2, e3);
                    run = e3 + i3;         // single dependent add per chunk
                }
                t[100] = run;              // total = entry 100
            }
        }
    }
    __syncthreads();

    // ---- scalar jump-scan WTA ----
    uint32_t m0 = 0, m1 = 0, m2 = 0, m3 = 0, m4 = 0;   // 149-bit spike mask
    if (x < NXS) {
        // single base + compile-time row offsets (encourages ds_read2 merges
        // for the uniform-index reads: kx-adjacent rows are 108 dwords apart)
        const uint32_t* Tq = tbl + (half * 27 + 2 * wave) * RSTRIDE;
        int tp = 1;                        // tp=0: empty window, no spike
        while (tp < TP) {
            const int t1 = tp - 1;
            const float ft1 = (float)t1;
            const int b0 = (tp < TT) ? tp : TT;          // uniform per wave
            uint32_t P0 = 0, P1 = 0, P2 = 0;
            float F = 0.0f;                // sum_j 48w_j * dc2_j
#pragma unroll
            for (int j = 0; j < 9; ++j) {
                const int roff = ((j / 3) * 9 + (j % 3)) * RSTRIDE; // const
                int i1 = t1 - mA[j]; i1 = i1 < 0 ? 0 : (i1 > TT ? TT : i1);
                int i2 = t1 - nA[j]; i2 = i2 < 0 ? 0 : (i2 > TT ? TT : i2);
                uint32_t p0 = Tq[roff + b0];
                uint32_t p1 = Tq[roff + i1];
                uint32_t p2 = Tq[roff + i2];
                P0 += p0; P1 += p1; P2 += p2;
                F += wA[j] * (float)(int)((p1 - p2) >> 16);
            }
            // packed sums/differences are carry-free: sum C <= 900 < 2^16,
            // sum M <= 9*4950 < 2^16.
            const uint32_t D1 = P0 - P1;   // rising window totals
            const uint32_t D2 = P1 - P2;   // falling window totals
            float pot = (ft1 * (float)(D1 >> 16) - (float)(D1 & 0xffffu)) * 0.0625f
                      + (F - ft1 * (float)(D2 >> 16) + (float)(D2 & 0xffffu)) * 0.03125f;
            pot += __shfl_xor(pot, 32);    // combine the two train halves

            if (__ballot(pot > 5.4f)) {    // any channel spikes this step?
                // argmax over 32 channels; ties -> lowest ch (jnp.argmax)
                float v = pot; int c = ch;
#pragma unroll
                for (int mk = 16; mk >= 1; mk >>= 1) {
                    float vo = __shfl_xor(v, mk);
                    int co   = __shfl_xor(c, mk);
                    if (vo > v || (vo == v && co < c)) { v = vo; c = co; }
                }
                if (c == ch) {
                    const uint32_t bit = 1u << (tp & 31);
                    switch (tp >> 5) {     // wave-uniform branch
                        case 0: m0 |= bit; break;
                        case 1: m1 |= bit; break;
                        case 2: m2 |= bit; break;
                        case 3: m3 |= bit; break;
                        default: m4 |= bit; break;
                    }
                }
                tp += 48;                  // dep=47 refractory skip
            } else {
                tp += 1;
            }
        }
    }

    // ---- stage masks, then block-cooperative contiguous NT write ----
    if (lane < 32) {                       // inactive wave stores zeros
        uint32_t* mm = mlds + (wave * 32 + ch) * 6;
        mm[0] = m0; mm[1] = m1; mm[2] = m2; mm[3] = m3; mm[4] = m4;
    }
    __syncthreads();

    const int nsite = (NXS - x0) < 4 ? (NXS - x0) : 4;
    const int span = nsite * TP;           // <= 596 contiguous dwords
    for (int c = 0; c < 32; ++c) {
        const size_t base = (((size_t)(b * 32 + c) * NXS + y) * NYS + x0) * TP;
        for (int d = tid; d < span; d += 256) {
            const int s = d / TP;
            const int t = d - s * TP;
            const uint32_t m = mlds[(s * 32 + c) * 6 + (t >> 5)];
            __builtin_nontemporal_store(((m >> (t & 31)) & 1u) ? 1.0f : 0.0f,
                                        out + base + d);
        }
    }
}

extern "C" void kernel_launch(void* const* d_in, const int* in_sizes, int n_in,
                              void* d_out, int out_size, void* d_ws, size_t ws_size,
                              hipStream_t stream) {
    const float* in = (const float*)d_in[0];   // input_spikes
    const float* wt = (const float*)d_in[1];   // weight
    float* out = (float*)d_out;

    // grid: 16 b x 31 y x 8 x-groups (last group covers 3 sites)
    hipLaunchKernelGGL(snn_wta, dim3(16 * NYS * 8), dim3(256), 0, stream,
                       in, wt, out);
}

// Round 9
// 402.911 us; speedup vs baseline: 1.0068x; 1.0068x over previous
//
#include <hip/hip_runtime.h>
#include <stdint.h>

// Spiking ConvColumn: temporal PWL-response conv + winner-takes-all.
//   input_spikes [16, 2, 64, 64, 100] fp32 (binary)
//   weight       [32, 2, 3, 3]        fp32 in [0,1]
//   output       [16, 32, 31, 31, 149] fp32 (one-hot spikes)
#define NXS 31
#define NYS 31
#define TP 149
#define TT 100
#define RSTRIDE 108         // u32/row: 101 entries + 7 spare; 108%32=12 ->
                            // b128 build stores <=2-way bank alias (free);
                            // 108%4==0 keeps 16-B alignment for b128.
#define NROWS 54            // 2 ci * 3 ky * 9 cols (4 sites share 9 cols)
#define LDS_TBL (NROWS * RSTRIDE)   // 5832 u32 = 23.3 KB
#define LDS_MSK (4 * 32 * 6)        // per-(site,ch) 5-word masks (pad to 6)
#define LDS_ACT 4                   // per-site active-channel maps

// Block = 4 waves = sites x0..x0+3 sharing one table set (9 columns).
// Wave lanes: 0-31 = 32 ch x trains 0-8 (ci=0); 32-63 = same ch x 9-17 (ci=1).
// Table entry k = (C[k]<<16)|M[k]: C = #spikes before time k, M = sum times.
__global__ __launch_bounds__(256) void snn_wta(
    const float* __restrict__ in,
    const float* __restrict__ weight,
    float* __restrict__ out)
{
    __shared__ uint32_t lds[LDS_TBL + LDS_MSK + LDS_ACT];
    uint32_t* tbl  = lds;
    uint32_t* mlds = lds + LDS_TBL;
    uint32_t* amap = lds + LDS_TBL + LDS_MSK;

    const int tid  = threadIdx.x;
    const int wave = tid >> 6;
    const int lane = tid & 63;
    const int half = lane >> 5;
    const int ch   = lane & 31;

    const int bi = blockIdx.x;
    const int xg = bi & 7;                // 8 x-groups of 4 (last has 3)
    const int y  = (bi >> 3) % NYS;
    const int b  = bi / (8 * NYS);
    const int x0 = xg * 4;
    const int x  = x0 + wave;             // this wave's site (x>=31 inactive)

    // per-lane response params: r(tau)=tau/16 for tau<=m=floor(16w);
    // (48w-tau)/32 for m<tau<=n=ceil(48w)-1.
    float wA[9]; int mA[9], nA[9];
    {
        const float* wrow = weight + ch * 18 + half * 9;
#pragma unroll
        for (int j = 0; j < 9; ++j) {
            float w = wrow[j];
            float a48 = 48.0f * w;
            int m = (int)floorf(16.0f * w);
            int n = (int)ceilf(a48) - 1;
            if (n < m) n = m;
            wA[j] = a48; mA[j] = m; nA[j] = n;
        }
    }

    // ---- build 54 rows; row r owned by one lane (waves split the rows).
    // Tree-form prefix: 25-step carry chain, b128 entry stores.
    {
        const int r = lane + 14 * wave;    // lanes 0..13 of each wave
        if (lane < 14 && r < NROWS) {
            const int ci = r / 27, rem = r % 27;
            const int ky = rem / 9, col = rem % 9;
            const int h = 2 * y + ky, wc = 2 * x0 + col;
            if (wc < 64) {                 // xg=7,col=8 is OOB and unused
                const float4* rowp = (const float4*)(in +
                    (size_t)(((b * 2 + ci) * 64 + h) * 64 + wc) * TT);
                uint32_t* t = tbl + r * RSTRIDE;      // entry-0, 16B aligned
                uint32_t run = 0;
#pragma unroll 5
                for (int chunk = 0; chunk < 25; ++chunk) {
                    float4 v = rowp[chunk];
                    const uint32_t u = chunk * 4;
                    uint32_t i0 = (v.x > 0.5f) ? ((1u << 16) | u)       : 0u;
                    uint32_t i1 = (v.y > 0.5f) ? ((1u << 16) | (u + 1)) : 0u;
                    uint32_t i2 = (v.z > 0.5f) ? ((1u << 16) | (u + 2)) : 0u;
                    uint32_t i3 = (v.w > 0.5f) ? ((1u << 16) | (u + 3)) : 0u;
                    uint32_t s01 = i0 + i1;
                    uint32_t e1 = run + i0;
                    uint32_t e2 = run + s01;
                    uint32_t e3 = e2 + i2;
                    *((uint4*)(t + u)) = make_uint4(run, e1, e2, e3);
                    run = e3 + i3;         // single dependent add per chunk
                }
                t[100] = run;              // total = entry 100
            }
        }
    }
    __syncthreads();

    // ---- scalar jump-scan WTA ----
    uint32_t m0 = 0, m1 = 0, m2 = 0, m3 = 0, m4 = 0;   // 149-bit spike mask
    if (x < NXS) {
        const uint32_t* Tq = tbl + (half * 27 + 2 * wave) * RSTRIDE;
        int tp = 1;                        // tp=0: empty window, no spike
        while (tp < TP) {
            const int t1 = tp - 1;
            const float ft1 = (float)t1;
            const int b0 = (tp < TT) ? tp : TT;          // uniform per wave
            uint32_t P0 = 0, P1 = 0, P2 = 0;
            float F = 0.0f;                // sum_j 48w_j * dc2_j
#pragma unroll
            for (int j = 0; j < 9; ++j) {
                const int roff = ((j / 3) * 9 + (j % 3)) * RSTRIDE; // const
                int i1 = t1 - mA[j]; i1 = i1 < 0 ? 0 : (i1 > TT ? TT : i1);
                int i2 = t1 - nA[j]; i2 = i2 < 0 ? 0 : (i2 > TT ? TT : i2);
                uint32_t p0 = Tq[roff + b0];
                uint32_t p1 = Tq[roff + i1];
                uint32_t p2 = Tq[roff + i2];
                P0 += p0; P1 += p1; P2 += p2;
                F += wA[j] * (float)(int)((p1 - p2) >> 16);
            }
            // packed sums/differences carry-free: sum C<=900, sum M<=44550.
            const uint32_t D1 = P0 - P1;   // rising window totals
            const uint32_t D2 = P1 - P2;   // falling window totals
            float pot = (ft1 * (float)(D1 >> 16) - (float)(D1 & 0xffffu)) * 0.0625f
                      + (F - ft1 * (float)(D2 >> 16) + (float)(D2 & 0xffffu)) * 0.03125f;
            pot += __shfl_xor(pot, 32);    // combine the two train halves

            if (__ballot(pot > 5.4f)) {    // any channel spikes this step?
                // argmax over 32 channels; ties -> lowest ch (jnp.argmax)
                float v = pot; int c = ch;
#pragma unroll
                for (int mk = 16; mk >= 1; mk >>= 1) {
                    float vo = __shfl_xor(v, mk);
                    int co   = __shfl_xor(c, mk);
                    if (vo > v || (vo == v && co < c)) { v = vo; c = co; }
                }
                if (c == ch) {
                    const uint32_t bit = 1u << (tp & 31);
                    switch (tp >> 5) {     // wave-uniform branch
                        case 0: m0 |= bit; break;
                        case 1: m1 |= bit; break;
                        case 2: m2 |= bit; break;
                        case 3: m3 |= bit; break;
                        default: m4 |= bit; break;
                    }
                }
                tp += 48;                  // dep=47 refractory skip
            } else {
                tp += 1;
            }
        }
    }

    // ---- stage masks + per-site active-channel maps ----
    const uint32_t any = (m0 | m1 | m2 | m3 | m4);
    const uint32_t act = (uint32_t)__ballot(any != 0u && lane < 32);
    if (lane < 32) {
        uint32_t* mm = mlds + (wave * 32 + ch) * 6;
        mm[0] = m0; mm[1] = m1; mm[2] = m2; mm[3] = m3; mm[4] = m4;
        if (lane == 0) amap[wave] = act;   // site's active channels
    }
    __syncthreads();
    const uint32_t blockact = amap[0] | amap[1] | amap[2] | amap[3];

    // ---- block-cooperative float4 epilogue over contiguous channel spans ----
    const int nsite = (NXS - x0) < 4 ? (NXS - x0) : 4;
    const int span = nsite * TP;           // <= 596 contiguous dwords
    const float4 z4 = make_float4(0.f, 0.f, 0.f, 0.f);
    for (int c = 0; c < 32; ++c) {
        const size_t base = (((size_t)(b * 32 + c) * NXS + y) * NYS + x0) * TP;
        const int a = (int)((4 - (base & 3)) & 3);   // head dwords to align
        const int nb = (span - a) >> 2;              // aligned float4 count
        const bool active = (blockact >> c) & 1u;

        // head + tail (at most 3 + 3 dwords), scalar
        if (tid < 4) {
            int d = tid;                             // head
            if (d < a) {
                int s = d / TP, t = d - s * TP;
                uint32_t m = active ? mlds[(s * 32 + c) * 6 + (t >> 5)] : 0u;
                out[base + d] = ((m >> (t & 31)) & 1u) ? 1.0f : 0.0f;
            }
            int d2 = a + 4 * nb + tid;               // tail
            if (d2 < span) {
                int s = d2 / TP, t = d2 - s * TP;
                uint32_t m = active ? mlds[(s * 32 + c) * 6 + (t >> 5)] : 0u;
                out[base + d2] = ((m >> (t & 31)) & 1u) ? 1.0f : 0.0f;
            }
        }
        // body: aligned float4 stores
        if (!active) {
            for (int i = tid; i < nb; i += 256)
                *((float4*)(out + base + a + 4 * i)) = z4;
        } else {
            for (int i = tid; i < nb; i += 256) {
                const int q = a + 4 * i;
                int s = q / TP, t = q - s * TP;
                float vv[4];
#pragma unroll
                for (int k = 0; k < 4; ++k) {
                    uint32_t m = mlds[(s * 32 + c) * 6 + (t >> 5)];
                    vv[k] = ((m >> (t & 31)) & 1u) ? 1.0f : 0.0f;
                    if (++t == TP) { t = 0; ++s; }   // site straddle
                }
                *((float4*)(out + base + q)) =
                    make_float4(vv[0], vv[1], vv[2], vv[3]);
            }
        }
    }
}

extern "C" void kernel_launch(void* const* d_in, const int* in_sizes, int n_in,
                              void* d_out, int out_size, void* d_ws, size_t ws_size,
                              hipStream_t stream) {
    const float* in = (const float*)d_in[0];   // input_spikes
    const float* wt = (const float*)d_in[1];   // weight
    float* out = (float*)d_out;

    // grid: 16 b x 31 y x 8 x-groups (last group covers 3 sites)
    hipLaunchKernelGGL(snn_wta, dim3(16 * NYS * 8), dim3(256), 0, stream,
                       in, wt, out);
}

// Round 10
// 381.659 us; speedup vs baseline: 1.0629x; 1.0557x over previous
//
#include <hip/hip_runtime.h>
#include <stdint.h>

// Spiking ConvColumn: temporal PWL-response conv + winner-takes-all.
//   input_spikes [16, 2, 64, 64, 100] fp32 (binary)
//   weight       [32, 2, 3, 3]        fp32 in [0,1]
//   output       [16, 32, 31, 31, 149] fp32 (one-hot spikes)
#define NXS 31
#define NYS 31
#define TP 149
#define TT 100
#define RSTRIDE 104         // u32/row: 101 entries + 3 spare; %4==0 keeps b128
                            // alignment; LDS = 54*104*4 = 22.5 KB -> 7 blk/CU
#define NROWS 54            // 2 ci * 3 ky * 9 cols (4 sites share 9 cols)
#define CSTRIDE 143189u     // 961*149, channel stride in d_out (odd: %4==1)

// Block = 4 waves = sites x0..x0+3 sharing one table set (9 columns).
// Wave lanes: 0-31 = 32 ch x trains 0-8 (ci=0); 32-63 = same ch x 9-17 (ci=1).
// Table entry k = (C[k]<<16)|M[k]: C = #spikes before time k, M = sum times.
__global__ __launch_bounds__(256) void snn_wta(
    const float* __restrict__ in,
    const float* __restrict__ weight,
    float* __restrict__ out)
{
    __shared__ uint32_t tbl[NROWS * RSTRIDE];

    const int tid  = threadIdx.x;
    const int wave = tid >> 6;
    const int lane = tid & 63;
    const int half = lane >> 5;
    const int ch   = lane & 31;

    const int bi = blockIdx.x;
    const int xg = bi & 7;                // 8 x-groups of 4 (last has 3)
    const int y  = (bi >> 3) % NYS;
    const int b  = bi / (8 * NYS);
    const int x0 = xg * 4;
    const int x  = x0 + wave;             // this wave's site (x>=31 inactive)

    // per-lane response params: r(tau)=tau/16 for tau<=m=floor(16w);
    // (48w-tau)/32 for m<tau<=n=ceil(48w)-1.
    float wA[9]; int mA[9], nA[9];
    {
        const float* wrow = weight + ch * 18 + half * 9;
#pragma unroll
        for (int j = 0; j < 9; ++j) {
            float w = wrow[j];
            float a48 = 48.0f * w;
            int m = (int)floorf(16.0f * w);
            int n = (int)ceilf(a48) - 1;
            if (n < m) n = m;
            wA[j] = a48; mA[j] = m; nA[j] = n;
        }
    }

    // ---- build 54 rows; row r owned by one lane (waves split the rows).
    // Tree-form prefix: 25-step carry chain, b128 entry stores.
    {
        const int r = lane + 14 * wave;    // lanes 0..13 of each wave
        if (lane < 14 && r < NROWS) {
            const int ci = r / 27, rem = r % 27;
            const int ky = rem / 9, col = rem % 9;
            const int h = 2 * y + ky, wc = 2 * x0 + col;
            if (wc < 64) {                 // xg=7,col=8 is OOB and unused
                const float4* rowp = (const float4*)(in +
                    (size_t)(((b * 2 + ci) * 64 + h) * 64 + wc) * TT);
                uint32_t* t = tbl + r * RSTRIDE;      // entry-0, 16B aligned
                uint32_t run = 0;
#pragma unroll 5
                for (int chunk = 0; chunk < 25; ++chunk) {
                    float4 v = rowp[chunk];
                    const uint32_t u = chunk * 4;
                    uint32_t i0 = (v.x > 0.5f) ? ((1u << 16) | u)       : 0u;
                    uint32_t i1 = (v.y > 0.5f) ? ((1u << 16) | (u + 1)) : 0u;
                    uint32_t i2 = (v.z > 0.5f) ? ((1u << 16) | (u + 2)) : 0u;
                    uint32_t i3 = (v.w > 0.5f) ? ((1u << 16) | (u + 3)) : 0u;
                    uint32_t s01 = i0 + i1;
                    uint32_t e1 = run + i0;
                    uint32_t e2 = run + s01;
                    uint32_t e3 = e2 + i2;
                    *((uint4*)(t + u)) = make_uint4(run, e1, e2, e3);
                    run = e3 + i3;         // single dependent add per chunk
                }
                t[100] = run;              // total = entry 100
            }
        }
    }
    __syncthreads();

    // ---- scalar jump-scan WTA ----
    uint32_t m0 = 0, m1 = 0, m2 = 0, m3 = 0, m4 = 0;   // 149-bit spike mask
    if (x < NXS) {
        const uint32_t* Tq = tbl + (half * 27 + 2 * wave) * RSTRIDE;
        int tp = 1;                        // tp=0: empty window, no spike
        while (tp < TP) {
            const int t1 = tp - 1;
            const float ft1 = (float)t1;
            const int b0 = (tp < TT) ? tp : TT;          // uniform per half
            uint32_t P0 = 0, P1 = 0, P2 = 0;
            float F = 0.0f;                // sum_j 48w_j * dc2_j
#pragma unroll
            for (int j = 0; j < 9; ++j) {
                const int roff = ((j / 3) * 9 + (j % 3)) * RSTRIDE; // const
                int i1 = t1 - mA[j]; i1 = i1 < 0 ? 0 : (i1 > TT ? TT : i1);
                int i2 = t1 - nA[j]; i2 = i2 < 0 ? 0 : (i2 > TT ? TT : i2);
                uint32_t p0 = Tq[roff + b0];
                uint32_t p1 = Tq[roff + i1];
                uint32_t p2 = Tq[roff + i2];
                P0 += p0; P1 += p1; P2 += p2;
                F += wA[j] * (float)(int)((p1 - p2) >> 16);
            }
            // packed sums/differences carry-free: sum C<=900, sum M<=44550.
            const uint32_t D1 = P0 - P1;   // rising window totals
            const uint32_t D2 = P1 - P2;   // falling window totals
            float pot = (ft1 * (float)(D1 >> 16) - (float)(D1 & 0xffffu)) * 0.0625f
                      + (F - ft1 * (float)(D2 >> 16) + (float)(D2 & 0xffffu)) * 0.03125f;
            pot += __shfl_xor(pot, 32);    // combine the two train halves

            if (__ballot(pot > 5.4f)) {    // any channel spikes this step?
                // argmax over 32 channels; ties -> lowest ch (jnp.argmax)
                float v = pot; int c = ch;
#pragma unroll
                for (int mk = 16; mk >= 1; mk >>= 1) {
                    float vo = __shfl_xor(v, mk);
                    int co   = __shfl_xor(c, mk);
                    if (vo > v || (vo == v && co < c)) { v = vo; c = co; }
                }
                if (c == ch) {
                    const uint32_t bit = 1u << (tp & 31);
                    switch (tp >> 5) {     // wave-uniform branch
                        case 0: m0 |= bit; break;
                        case 1: m1 |= bit; break;
                        case 2: m2 |= bit; break;
                        case 3: m3 |= bit; break;
                        default: m4 |= bit; break;
                    }
                }
                tp += 48;                  // dep=47 refractory skip
            } else {
                tp += 1;
            }
        }
    }

    // ---- epilogue part 1: block-wide float4 ZERO-fill of the 4-site span.
    // No mask decode at all: the output is zeros except the scattered ones.
    const int nsite = (NXS - x0) < 4 ? (NXS - x0) : 4;
    const int span = nsite * TP;           // 447 or 596 contiguous dwords
    const uint32_t base0 =
        ((uint32_t)(b * 32) * 961u + (uint32_t)(y * NYS + x0)) * (uint32_t)TP;
    const float4 z4 = make_float4(0.f, 0.f, 0.f, 0.f);

    // head + tail dwords (alignment rotates per channel: CSTRIDE % 4 == 1).
    {
        const int c = tid >> 3, slot = tid & 7;      // 32 ch x 8 slots
        const uint32_t st = base0 + (uint32_t)c * CSTRIDE;
        const int a = (int)((0u - st) & 3u);
        const int nb = (span - a) >> 2;
        const int tail = span - a - 4 * nb;          // 0..3
        if (slot < a)                out[(size_t)st + slot] = 0.0f;
        else if (slot >= 3 && slot - 3 < tail)
            out[(size_t)st + a + 4 * nb + (slot - 3)] = 0.0f;
    }
    // aligned float4 body: flattened over (channel, chunk), 19 iters/thread
    for (int i = tid; i < 32 * 152; i += 256) {
        const int c = i / 152, k = i - c * 152;
        const uint32_t st = base0 + (uint32_t)c * CSTRIDE;
        const int a = (int)((0u - st) & 3u);
        const int nb = (span - a) >> 2;
        if (k < nb)
            *((float4*)(out + (size_t)st + a) + k) = z4;
    }
    __syncthreads();   // barrier drains vmcnt -> zeros land before the ones

    // ---- epilogue part 2: scatter the 1.0s straight from mask registers ----
    if (x < NXS && lane < 32) {
        const size_t rb = (size_t)(((b * 32 + ch) * 961) + y * NYS + x) * TP;
        uint32_t mw[5] = { m0, m1, m2, m3, m4 };
#pragma unroll
        for (int w = 0; w < 5; ++w) {
            uint32_t mm = mw[w];
            while (mm) {                   // <=4 spikes total per (site,ch)
                const int t = __builtin_ctz(mm);
                mm &= mm - 1;
                out[rb + 32 * w + t] = 1.0f;
            }
        }
    }
}

extern "C" void kernel_launch(void* const* d_in, const int* in_sizes, int n_in,
                              void* d_out, int out_size, void* d_ws, size_t ws_size,
                              hipStream_t stream) {
    const float* in = (const float*)d_in[0];   // input_spikes
    const float* wt = (const float*)d_in[1];   // weight
    float* out = (float*)d_out;

    // grid: 16 b x 31 y x 8 x-groups (last group covers 3 sites)
    hipLaunchKernelGGL(snn_wta, dim3(16 * NYS * 8), dim3(256), 0, stream,
                       in, wt, out);
}